// Round 6
// baseline (557.820 us; speedup 1.0000x reference)
//
#include <hip/hip_runtime.h>
#include <math.h>

// ---------------------------------------------------------------------------
// PAPE Transformer encoder layer, MI355X/gfx950.  Round 6:
//  - attn: R5 counted-vmcnt skeleton +
//    (a) XCD head-grouping (bid&7 -> XCD owns 2 heads; K/V L2-resident,
//        kills ~140MB HBM re-fetch),
//    (b) bias stream as 4x global_load_dwordx4 per wave/iter (256B runs),
//        depth-2 register pipeline (rA/rB), written late to a per-wave
//        private LDS tile (no barrier), read back in softmax,
//    (c) end-of-iter s_waitcnt vmcnt(4): bias loads live across barrier.
//    LDS = 80KB exactly -> 2 blocks/CU.
//  - GEMMs / LN / split-K / transpose unchanged.
// ---------------------------------------------------------------------------

using bf16_t = __bf16;
using bf16x8 = __attribute__((ext_vector_type(8))) __bf16;
using bf16x4 = __attribute__((ext_vector_type(4))) __bf16;
using f32x4  = __attribute__((ext_vector_type(4))) float;

#define DEV_INLINE __device__ __forceinline__

DEV_INLINE void lds_load16(const void* g, void* l) {
  __builtin_amdgcn_global_load_lds(
      (__attribute__((address_space(1))) void*)(g),
      (__attribute__((address_space(3))) void*)(l), 16, 0, 0);
}

// swizzled 8x bf16 read from a [rows][64] bf16 tile (128B rows):
// element chunk c of row r lives at byte r*128 + ((c ^ (r&7))<<4)
DEV_INLINE bf16x8 lds_read8_sw(const bf16_t* base, int row, int chunk) {
  return *(const bf16x8*)((const char*)base + row * 128 + (((chunk) ^ (row & 7)) << 4));
}

// ---------------------------------------------------------------------------
__global__ __launch_bounds__(256)
void f32_to_bf16_k(const float* __restrict__ in, bf16_t* __restrict__ out, int n) {
  int i = (blockIdx.x * 256 + threadIdx.x) * 4;
  if (i >= n) return;
  float4 v = *(const float4*)(in + i);
  bf16x4 o = {(bf16_t)v.x, (bf16_t)v.y, (bf16_t)v.z, (bf16_t)v.w};
  *(bf16x4*)(out + i) = o;
}

__global__ __launch_bounds__(256)
void copy_f32_k(const float* __restrict__ in, float* __restrict__ out, int n) {
  int i = blockIdx.x * 256 + threadIdx.x;
  if (i < n) out[i] = in[i];
}

// ---------------------------------------------------------------------------
// GEMM: out[M,N] = A[M,K] @ Bw[N,K]^T (+ bias / epilogue)  — unchanged
// ---------------------------------------------------------------------------
template <int MODE>
__global__ __launch_bounds__(256)
void gemm_bt(const bf16_t* __restrict__ A, int lda,
             const bf16_t* __restrict__ Bw, int ldb,
             const float* __restrict__ bias,
             void* __restrict__ outp, int M, int N, int K) {
  __shared__ bf16_t sA[128 * 32];
  __shared__ bf16_t sB[128 * 32];

  const int tid  = threadIdx.x;
  const int lane = tid & 63, wid = tid >> 6;
  const int wr = wid >> 1, wc = wid & 1;
  const int brow = blockIdx.y, bcol = blockIdx.x;
  const int lm = lane & 15, lk = lane >> 4;
  const int z = blockIdx.z;

  A  += (size_t)z * K;
  Bw += (size_t)z * K;

  f32x4 zero = {0.f, 0.f, 0.f, 0.f};
  f32x4 acc[4][4];
#pragma unroll
  for (int i = 0; i < 4; ++i)
#pragma unroll
    for (int j = 0; j < 4; ++j) acc[i][j] = zero;

  const int srow = wid * 16 + (lane >> 2);
  const int scol = (lane & 3) * 8;
  const bf16_t* Abase = A  + (size_t)(brow * 128 + srow) * lda + scol;
  const bf16_t* Bbase = Bw + (size_t)(bcol * 128 + srow) * ldb + scol;
  char* sAw = (char*)sA + wid * 1024;
  char* sBw = (char*)sB + wid * 1024;

  for (int kk = 0; kk < K; kk += 32) {
    lds_load16(Abase + kk,                    sAw);
    lds_load16(Abase + (size_t)64 * lda + kk, sAw + 4096);
    lds_load16(Bbase + kk,                    sBw);
    lds_load16(Bbase + (size_t)64 * ldb + kk, sBw + 4096);
    __syncthreads();

    bf16x8 a[4], b[4];
#pragma unroll
    for (int mi = 0; mi < 4; ++mi)
      a[mi] = *(const bf16x8*)(sA + (wr * 64 + mi * 16 + lm) * 32 + lk * 8);
#pragma unroll
    for (int ni = 0; ni < 4; ++ni)
      b[ni] = *(const bf16x8*)(sB + (wc * 64 + ni * 16 + lm) * 32 + lk * 8);
    __builtin_amdgcn_s_setprio(1);
#pragma unroll
    for (int mi = 0; mi < 4; ++mi)
#pragma unroll
      for (int ni = 0; ni < 4; ++ni)
        acc[mi][ni] = __builtin_amdgcn_mfma_f32_16x16x32_bf16(a[mi], b[ni], acc[mi][ni], 0, 0, 0);
    __builtin_amdgcn_s_setprio(0);
    __syncthreads();
  }

#pragma unroll
  for (int mi = 0; mi < 4; ++mi) {
#pragma unroll
    for (int ni = 0; ni < 4; ++ni) {
#pragma unroll
      for (int j = 0; j < 4; ++j) {
        int row = brow * 128 + wr * 64 + mi * 16 + lk * 4 + j;
        int col = bcol * 128 + wc * 64 + ni * 16 + lm;
        if (MODE == 3) {
          ((float*)outp)[(size_t)z * M * N + (size_t)row * N + col] = acc[mi][ni][j];
        } else {
          float v = acc[mi][ni][j] + bias[col];
          if (MODE == 1) v = 0.5f * v * (1.f + erff(v * 0.70710678118f));
          ((bf16_t*)outp)[(size_t)row * N + col] = (bf16_t)v;
        }
      }
    }
  }
}

// ---------------------------------------------------------------------------
// V transpose: qkv[b, s, 2048 + h*64 + d] -> vt[(b*16+h)*64 + d, s] — unchanged
// ---------------------------------------------------------------------------
__global__ __launch_bounds__(256)
void transpose_v(const bf16_t* __restrict__ qkv, bf16_t* __restrict__ vt) {
  __shared__ bf16_t tile[64][65];
  const int bid = blockIdx.x;
  const int st = bid & 31, h = (bid >> 5) & 15, b = bid >> 9;
  const int tid = threadIdx.x;
  const int r = tid >> 3, c0 = (tid & 7) * 8;
#pragma unroll
  for (int p = 0; p < 2; ++p) {
    int rr = p * 32 + r;
    const bf16_t* g = qkv + (size_t)(b * 2048 + st * 64 + rr) * 3072 + 2048 + h * 64 + c0;
    bf16x8 v = *(const bf16x8*)g;
#pragma unroll
    for (int i = 0; i < 8; ++i) tile[rr][c0 + i] = v[i];
  }
  __syncthreads();
#pragma unroll
  for (int p = 0; p < 2; ++p) {
    int d = p * 32 + r;
    bf16x8 o;
#pragma unroll
    for (int i = 0; i < 8; ++i) o[i] = tile[c0 + i][d];
    *(bf16x8*)(vt + ((size_t)(b * 16 + h) * 64 + d) * 2048 + st * 64 + c0) = o;
  }
}

// ---------------------------------------------------------------------------
// Flash attention with additive relative bias — counted-vmcnt pipeline v2.
// Grid 512, 8 waves (512 thr). XCD x = bid&7 owns heads {2x,2x+1} so each
// XCD's K/V working set (2MB) fits its private L2.
// Bias: 4x dwordx4 per wave/iter, depth-2 reg pipeline, written late into a
// per-wave-private LDS tile; end-of-iter s_waitcnt vmcnt(4) keeps the 4 bias
// loads in flight across the barrier.
// ---------------------------------------------------------------------------
__global__ __launch_bounds__(512, 4)
void attn_k(const bf16_t* __restrict__ qkv, const bf16_t* __restrict__ vt,
            const float* __restrict__ bias, bf16_t* __restrict__ outp) {
  __shared__ bf16_t Ks[2][64 * 64];          // 16 KB
  __shared__ bf16_t Vs[2][64 * 64];          // 16 KB
  __shared__ bf16_t Ps[8][16 * 64];          // 16 KB
  __shared__ float  Bs[8][16 * 64];          // 32 KB  (per-wave bias tile)

  const int bid = blockIdx.x;                // XCD-grouped decode
  const int x  = bid & 7;                    // XCD (round-robin dispatch)
  const int r_ = bid >> 3;                   // 0..63
  const int h  = x * 2 + (r_ & 1);
  const int b  = (r_ >> 1) & 1;
  const int qt = r_ >> 2;                    // 0..15

  const int tid = threadIdx.x;               // 0..511
  const int lane = tid & 63, wid = tid >> 6;
  const int lm = lane & 15, lk = lane >> 4;

  // K/V staging (inverse-swizzled global source, linear LDS dest)
  const int sr  = tid >> 3;                       // 0..63
  const int sc_ = (((tid & 7) ^ (sr & 7)) * 8);
  const bf16_t* kgb = qkv + 1024 + (size_t)(b * 2048 + sr) * 3072 + h * 64 + sc_;
  const bf16_t* vgb = vt + ((size_t)((b * 16 + h) * 64) + sr) * 2048 + sc_;

  auto stageKV = [&](int kt, int buf) {
    lds_load16(kgb + (size_t)(kt * 64) * 3072, (char*)Ks + buf * 8192 + wid * 1024);
    lds_load16(vgb + kt * 64,                  (char*)Vs + buf * 8192 + wid * 1024);
  };

  // Q fragments direct from global (one-time)
  bf16x8 qa[2];
#pragma unroll
  for (int ks = 0; ks < 2; ++ks)
    qa[ks] = *(const bf16x8*)(qkv +
        (size_t)(b * 2048 + qt * 128 + wid * 16 + lm) * 3072 + h * 64 + ks * 32 + lk * 8);

  f32x4 zero = {0.f, 0.f, 0.f, 0.f};
  f32x4 acc_o[4];
  float m_run[4], l_run[4];
#pragma unroll
  for (int j = 0; j < 4; ++j) { acc_o[j] = zero; m_run[j] = -1e30f; l_run[j] = 0.f; }

  bf16_t* PsW   = &Ps[wid][0];
  float*  biasW = &Bs[wid][0];

  // bias vector-load base: lane covers row (lane>>4), 16B col chunk (lane&15)
  const float* bias_f4 = bias + (size_t)h * 2048 * 2048 +
      (size_t)(qt * 128 + wid * 16 + (lane >> 4)) * 2048 + (lane & 15) * 4;

  float4 rA[4], rB[4];

  // ---- prologue ----
  // tile 0 -> rA -> Bs (per-wave private, no barrier needed)
#pragma unroll
  for (int i = 0; i < 4; ++i)
    rA[i] = *(const float4*)(bias_f4 + (size_t)(i * 4) * 2048);
#pragma unroll
  for (int i = 0; i < 4; ++i)
    *(float4*)(biasW + (i * 4 + (lane >> 4)) * 64 + (lane & 15) * 4) = rA[i];
  // stage K/V tile 0, then bias tile 1 -> rB (stage older in vmcnt FIFO)
  stageKV(0, 0);
#pragma unroll
  for (int i = 0; i < 4; ++i)
    rB[i] = *(const float4*)(bias_f4 + (size_t)(i * 4) * 2048 + 64);
  __builtin_amdgcn_sched_barrier(0);
  asm volatile("s_waitcnt vmcnt(4)" ::: "memory");  // stage(0) done; rB in flight
  __builtin_amdgcn_s_barrier();
  asm volatile("" ::: "memory");

  auto body = [&](int kt, float4 (&rc)[4], float4 (&rn)[4]) {
    const int cur  = kt & 1;
    const int ktn  = (kt + 1 < 32) ? kt + 1 : 31;   // K/V stage clamp
    const int ktn2 = (kt + 2 < 32) ? kt + 2 : 31;   // bias load clamp
    stageKV(ktn, cur ^ 1);
#pragma unroll
    for (int i = 0; i < 4; ++i)
      rn[i] = *(const float4*)(bias_f4 + (size_t)(i * 4) * 2048 + ktn2 * 64);
    __builtin_amdgcn_sched_barrier(0);              // pin issue-early

    const bf16_t* Kcur = (const bf16_t*)((const char*)Ks + cur * 8192);
    const bf16_t* Vcur = (const bf16_t*)((const char*)Vs + cur * 8192);

    // QK^T from LDS
    f32x4 sc[4];
#pragma unroll
    for (int ni = 0; ni < 4; ++ni) sc[ni] = zero;
    __builtin_amdgcn_s_setprio(1);
#pragma unroll
    for (int ks = 0; ks < 2; ++ks) {
#pragma unroll
      for (int ni = 0; ni < 4; ++ni) {
        bf16x8 kb = lds_read8_sw(Kcur, ni * 16 + lm, ks * 4 + lk);
        sc[ni] = __builtin_amdgcn_mfma_f32_16x16x32_bf16(qa[ks], kb, sc[ni], 0, 0, 0);
      }
    }
    __builtin_amdgcn_s_setprio(0);

    // scores = sc/8 + bias (bias tile kt from per-wave LDS)
#pragma unroll
    for (int ni = 0; ni < 4; ++ni)
#pragma unroll
      for (int j = 0; j < 4; ++j)
        sc[ni][j] = sc[ni][j] * 0.125f + biasW[(lk * 4 + j) * 64 + ni * 16 + lm];

    float mloc[4], rs[4], scl[4];
#pragma unroll
    for (int j = 0; j < 4; ++j)
      mloc[j] = fmaxf(fmaxf(sc[0][j], sc[1][j]), fmaxf(sc[2][j], sc[3][j]));
#pragma unroll
    for (int off = 1; off < 16; off <<= 1)
#pragma unroll
      for (int j = 0; j < 4; ++j)
        mloc[j] = fmaxf(mloc[j], __shfl_xor(mloc[j], off, 64));

#pragma unroll
    for (int j = 0; j < 4; ++j) {
      float mnew = fmaxf(m_run[j], mloc[j]);
      scl[j] = __expf(m_run[j] - mnew);
      m_run[j] = mnew;
      rs[j] = 0.f;
#pragma unroll
      for (int ni = 0; ni < 4; ++ni) { sc[ni][j] = __expf(sc[ni][j] - mnew); rs[j] += sc[ni][j]; }
    }
#pragma unroll
    for (int off = 1; off < 16; off <<= 1)
#pragma unroll
      for (int j = 0; j < 4; ++j)
        rs[j] += __shfl_xor(rs[j], off, 64);
#pragma unroll
    for (int j = 0; j < 4; ++j) l_run[j] = l_run[j] * scl[j] + rs[j];
#pragma unroll
    for (int nf = 0; nf < 4; ++nf)
#pragma unroll
      for (int j = 0; j < 4; ++j) acc_o[nf][j] *= scl[j];

    // P -> LDS (own wave region, swizzled; same-wave RAW via lgkmcnt)
#pragma unroll
    for (int ni = 0; ni < 4; ++ni)
#pragma unroll
      for (int j = 0; j < 4; ++j) {
        int rr = lk * 4 + j;
        *(bf16_t*)((char*)PsW + rr * 128 + (((ni * 2 + (lm >> 3)) ^ (rr & 7)) << 4) + (lm & 7) * 2)
            = (bf16_t)sc[ni][j];
      }

    // PV
#pragma unroll
    for (int ks = 0; ks < 2; ++ks) {
      bf16x8 pa = lds_read8_sw(PsW, lm, ks * 4 + lk);
      __builtin_amdgcn_s_setprio(1);
#pragma unroll
      for (int nf = 0; nf < 4; ++nf) {
        bf16x8 vb = lds_read8_sw(Vcur, nf * 16 + lm, ks * 4 + lk);
        acc_o[nf] = __builtin_amdgcn_mfma_f32_16x16x32_bf16(pa, vb, acc_o[nf], 0, 0, 0);
      }
      __builtin_amdgcn_s_setprio(0);
    }

    // write bias tile kt+1 (rc, loaded last iter) into per-wave LDS — late
#pragma unroll
    for (int i = 0; i < 4; ++i)
      *(float4*)(biasW + (i * 4 + (lane >> 4)) * 64 + (lane & 15) * 4) = rc[i];

    // retire K/V stage; keep the 4 rn bias loads in flight across barrier
    asm volatile("s_waitcnt vmcnt(4)" ::: "memory");
    __builtin_amdgcn_s_barrier();
    asm volatile("" ::: "memory");
  };

  for (int kt2 = 0; kt2 < 32; kt2 += 2) {
    body(kt2,     rB, rA);
    body(kt2 + 1, rA, rB);
  }

#pragma unroll
  for (int nf = 0; nf < 4; ++nf) {
#pragma unroll
    for (int j = 0; j < 4; ++j) {
      float o = acc_o[nf][j] / l_run[j];
      outp[(size_t)(b * 2048 + qt * 128 + wid * 16 + lk * 4 + j) * 1024 + h * 64 + nf * 16 + lm] = (bf16_t)o;
    }
  }
}

// ---------------------------------------------------------------------------
// Fused LayerNorm over last dim (1024):  in = pa + pb + bias + resid — unchanged
// ---------------------------------------------------------------------------
__global__ __launch_bounds__(256)
void layernorm2_k(const float* __restrict__ pa, const float* __restrict__ pb,
                  const float* __restrict__ bias, const float* __restrict__ resid,
                  const float* __restrict__ gamma, const float* __restrict__ beta,
                  float* __restrict__ out32, bf16_t* __restrict__ out16) {
  const int row = blockIdx.x, tid = threadIdx.x;
  const int lane = tid & 63, wid = tid >> 6;
  const size_t base = (size_t)row * 1024;
  float4 v  = ((const float4*)(pa + base))[tid];
  float4 v2 = ((const float4*)(pb + base))[tid];
  float4 bb = ((const float4*)bias)[tid];
  float4 rr = ((const float4*)(resid + base))[tid];
  v.x += v2.x + bb.x + rr.x;
  v.y += v2.y + bb.y + rr.y;
  v.z += v2.z + bb.z + rr.z;
  v.w += v2.w + bb.w + rr.w;
  float s  = v.x + v.y + v.z + v.w;
  float s2 = v.x * v.x + v.y * v.y + v.z * v.z + v.w * v.w;
#pragma unroll
  for (int off = 32; off; off >>= 1) {
    s  += __shfl_xor(s, off, 64);
    s2 += __shfl_xor(s2, off, 64);
  }
  __shared__ float red[8];
  if (lane == 0) { red[wid] = s; red[wid + 4] = s2; }
  __syncthreads();
  s  = red[0] + red[1] + red[2] + red[3];
  s2 = red[4] + red[5] + red[6] + red[7];
  const float mu  = s * (1.f / 1024.f);
  const float inv = rsqrtf(s2 * (1.f / 1024.f) - mu * mu + 1e-5f);
  const float4 g4 = ((const float4*)gamma)[tid];
  const float4 b4 = ((const float4*)beta)[tid];
  float4 o;
  o.x = (v.x - mu) * inv * g4.x + b4.x;
  o.y = (v.y - mu) * inv * g4.y + b4.y;
  o.z = (v.z - mu) * inv * g4.z + b4.z;
  o.w = (v.w - mu) * inv * g4.w + b4.w;
  ((float4*)(out32 + base))[tid] = o;
  if (out16) {
    bf16x4 ob = {(bf16_t)o.x, (bf16_t)o.y, (bf16_t)o.z, (bf16_t)o.w};
    *(bf16x4*)(out16 + base + tid * 4) = ob;
  }
}

// ---------------------------------------------------------------------------
extern "C" void kernel_launch(void* const* d_in, const int* in_sizes, int n_in,
                              void* d_out, int out_size, void* d_ws, size_t ws_size,
                              hipStream_t stream) {
  const float* src  = (const float*)d_in[0];
  const float* rbias= (const float*)d_in[1];
  const float* Wq   = (const float*)d_in[2];
  const float* bq   = (const float*)d_in[3];
  const float* Wk   = (const float*)d_in[4];
  const float* bk   = (const float*)d_in[5];
  const float* Wv   = (const float*)d_in[6];
  const float* bv   = (const float*)d_in[7];
  const float* Wo   = (const float*)d_in[8];
  const float* bo   = (const float*)d_in[9];
  const float* W1   = (const float*)d_in[10];
  const float* b1   = (const float*)d_in[11];
  const float* W2   = (const float*)d_in[12];
  const float* b2   = (const float*)d_in[13];
  const float* g1   = (const float*)d_in[14];
  const float* be1  = (const float*)d_in[15];
  const float* g2   = (const float*)d_in[16];
  const float* be2  = (const float*)d_in[17];

  char* ws = (char*)d_ws;
  const size_t MB = 1u << 20;
  bf16_t* src_bf  = (bf16_t*)(ws + 0);        //  8 MB [4096,1024]
  bf16_t* wqkv_bf = (bf16_t*)(ws + 8 * MB);   //  6 MB [3072,1024]
  bf16_t* wo_bf   = (bf16_t*)(ws + 14 * MB);  //  2 MB
  bf16_t* w1_bf   = (bf16_t*)(ws + 16 * MB);  //  8 MB [4096,1024]
  bf16_t* w2_bf   = (bf16_t*)(ws + 24 * MB);  //  8 MB [1024,4096]
  float*  bqkv    = (float*)(ws + 32 * MB);   // 12 KB
  bf16_t* qkv_bf  = (bf16_t*)(ws + 33 * MB);  // 24 MB [4096,3072]
  bf16_t* vt      = (bf16_t*)(ws + 57 * MB);  //  8 MB [32*64,2048]
  bf16_t* attn_bf = (bf16_t*)(ws + 65 * MB);  //  8 MB [4096,1024]
  float*  pA      = (float*)(ws + 73 * MB);   // 16 MB split-K partial 0
  float*  pB      = (float*)(ws + 89 * MB);   // 16 MB split-K partial 1
  float*  xf      = (float*)(ws + 105 * MB);  // 16 MB
  bf16_t* x_bf    = (bf16_t*)(ws + 121 * MB); //  8 MB
  bf16_t* h_bf    = (bf16_t*)(ws + 129 * MB); // 32 MB [4096,4096]  (total 161)

  auto cvt = [&](const float* s, bf16_t* d, int n) {
    f32_to_bf16_k<<<n / 1024, 256, 0, stream>>>(s, d, n);
  };
  cvt(src, src_bf, 4096 * 1024);
  cvt(Wq, wqkv_bf,                   1024 * 1024);
  cvt(Wk, wqkv_bf + 1024 * 1024,     1024 * 1024);
  cvt(Wv, wqkv_bf + 2 * 1024 * 1024, 1024 * 1024);
  cvt(Wo, wo_bf, 1024 * 1024);
  cvt(W1, w1_bf, 4096 * 1024);
  cvt(W2, w2_bf, 4096 * 1024);
  copy_f32_k<<<4, 256, 0, stream>>>(bq, bqkv, 1024);
  copy_f32_k<<<4, 256, 0, stream>>>(bk, bqkv + 1024, 1024);
  copy_f32_k<<<4, 256, 0, stream>>>(bv, bqkv + 2048, 1024);

  // fused QKV projection: [4096,3072]
  gemm_bt<0><<<dim3(24, 32), 256, 0, stream>>>(
      src_bf, 1024, wqkv_bf, 1024, bqkv, qkv_bf, 4096, 3072, 1024);
  transpose_v<<<1024, 256, 0, stream>>>(qkv_bf, vt);
  attn_k<<<512, 512, 0, stream>>>(qkv_bf, vt, rbias, attn_bf);

  // output projection, split-K=2 -> partials; LN1 fuses +bo+src
  gemm_bt<3><<<dim3(8, 32, 2), 256, 0, stream>>>(
      attn_bf, 1024, wo_bf, 1024, nullptr, pA, 4096, 1024, 512);
  layernorm2_k<<<4096, 256, 0, stream>>>(pA, pB, bo, src, g1, be1, xf, x_bf);

  // FFN1 + exact GELU
  gemm_bt<1><<<dim3(32, 32), 256, 0, stream>>>(
      x_bf, 1024, w1_bf, 1024, b1, h_bf, 4096, 4096, 1024);

  // FFN2, split-K=2 -> partials; LN2 fuses +b2+xf
  gemm_bt<3><<<dim3(8, 32, 2), 256, 0, stream>>>(
      h_bf, 4096, w2_bf, 4096, nullptr, pA, 4096, 1024, 2048);
  layernorm2_k<<<4096, 256, 0, stream>>>(pA, pB, b2, xf, g2, be2, (float*)d_out, nullptr);
}

// Round 7
// 460.542 us; speedup vs baseline: 1.2112x; 1.2112x over previous
//
#include <hip/hip_runtime.h>
#include <math.h>

// ---------------------------------------------------------------------------
// PAPE Transformer encoder layer, MI355X/gfx950.  Round 7:
//  - attn: R5 register-bias scheme + R6 XCD head-grouping, with the spill
//    bug fixed: body is a macro, bias double-buffers bbA/bbB only ever
//    indexed by constants (never address-taken) -> stay in VGPRs across the
//    asm "memory" clobbers. No bias LDS tile. Per iter: 2 gload_lds (K/V)
//    + 16 bias dwords issued first; s_waitcnt vmcnt(16) + s_barrier at end
//    keeps all 16 bias HBM loads in flight across the barrier.
//    LDS 48KB, grid 512, 8 waves, launch_bounds(512,4).
//  - GEMMs / LN / split-K / transpose unchanged.
// ---------------------------------------------------------------------------

using bf16_t = __bf16;
using bf16x8 = __attribute__((ext_vector_type(8))) __bf16;
using bf16x4 = __attribute__((ext_vector_type(4))) __bf16;
using f32x4  = __attribute__((ext_vector_type(4))) float;

#define DEV_INLINE __device__ __forceinline__

DEV_INLINE void lds_load16(const void* g, void* l) {
  __builtin_amdgcn_global_load_lds(
      (__attribute__((address_space(1))) void*)(g),
      (__attribute__((address_space(3))) void*)(l), 16, 0, 0);
}

// swizzled 8x bf16 read from a [rows][64] bf16 tile (128B rows):
// element chunk c of row r lives at byte r*128 + ((c ^ (r&7))<<4)
DEV_INLINE bf16x8 lds_read8_sw(const bf16_t* base, int row, int chunk) {
  return *(const bf16x8*)((const char*)base + row * 128 + (((chunk) ^ (row & 7)) << 4));
}

// ---------------------------------------------------------------------------
__global__ __launch_bounds__(256)
void f32_to_bf16_k(const float* __restrict__ in, bf16_t* __restrict__ out, int n) {
  int i = (blockIdx.x * 256 + threadIdx.x) * 4;
  if (i >= n) return;
  float4 v = *(const float4*)(in + i);
  bf16x4 o = {(bf16_t)v.x, (bf16_t)v.y, (bf16_t)v.z, (bf16_t)v.w};
  *(bf16x4*)(out + i) = o;
}

__global__ __launch_bounds__(256)
void copy_f32_k(const float* __restrict__ in, float* __restrict__ out, int n) {
  int i = blockIdx.x * 256 + threadIdx.x;
  if (i < n) out[i] = in[i];
}

// ---------------------------------------------------------------------------
// GEMM: out[M,N] = A[M,K] @ Bw[N,K]^T (+ bias / epilogue)  — unchanged
// ---------------------------------------------------------------------------
template <int MODE>
__global__ __launch_bounds__(256)
void gemm_bt(const bf16_t* __restrict__ A, int lda,
             const bf16_t* __restrict__ Bw, int ldb,
             const float* __restrict__ bias,
             void* __restrict__ outp, int M, int N, int K) {
  __shared__ bf16_t sA[128 * 32];
  __shared__ bf16_t sB[128 * 32];

  const int tid  = threadIdx.x;
  const int lane = tid & 63, wid = tid >> 6;
  const int wr = wid >> 1, wc = wid & 1;
  const int brow = blockIdx.y, bcol = blockIdx.x;
  const int lm = lane & 15, lk = lane >> 4;
  const int z = blockIdx.z;

  A  += (size_t)z * K;
  Bw += (size_t)z * K;

  f32x4 zero = {0.f, 0.f, 0.f, 0.f};
  f32x4 acc[4][4];
#pragma unroll
  for (int i = 0; i < 4; ++i)
#pragma unroll
    for (int j = 0; j < 4; ++j) acc[i][j] = zero;

  const int srow = wid * 16 + (lane >> 2);
  const int scol = (lane & 3) * 8;
  const bf16_t* Abase = A  + (size_t)(brow * 128 + srow) * lda + scol;
  const bf16_t* Bbase = Bw + (size_t)(bcol * 128 + srow) * ldb + scol;
  char* sAw = (char*)sA + wid * 1024;
  char* sBw = (char*)sB + wid * 1024;

  for (int kk = 0; kk < K; kk += 32) {
    lds_load16(Abase + kk,                    sAw);
    lds_load16(Abase + (size_t)64 * lda + kk, sAw + 4096);
    lds_load16(Bbase + kk,                    sBw);
    lds_load16(Bbase + (size_t)64 * ldb + kk, sBw + 4096);
    __syncthreads();

    bf16x8 a[4], b[4];
#pragma unroll
    for (int mi = 0; mi < 4; ++mi)
      a[mi] = *(const bf16x8*)(sA + (wr * 64 + mi * 16 + lm) * 32 + lk * 8);
#pragma unroll
    for (int ni = 0; ni < 4; ++ni)
      b[ni] = *(const bf16x8*)(sB + (wc * 64 + ni * 16 + lm) * 32 + lk * 8);
    __builtin_amdgcn_s_setprio(1);
#pragma unroll
    for (int mi = 0; mi < 4; ++mi)
#pragma unroll
      for (int ni = 0; ni < 4; ++ni)
        acc[mi][ni] = __builtin_amdgcn_mfma_f32_16x16x32_bf16(a[mi], b[ni], acc[mi][ni], 0, 0, 0);
    __builtin_amdgcn_s_setprio(0);
    __syncthreads();
  }

#pragma unroll
  for (int mi = 0; mi < 4; ++mi) {
#pragma unroll
    for (int ni = 0; ni < 4; ++ni) {
#pragma unroll
      for (int j = 0; j < 4; ++j) {
        int row = brow * 128 + wr * 64 + mi * 16 + lk * 4 + j;
        int col = bcol * 128 + wc * 64 + ni * 16 + lm;
        if (MODE == 3) {
          ((float*)outp)[(size_t)z * M * N + (size_t)row * N + col] = acc[mi][ni][j];
        } else {
          float v = acc[mi][ni][j] + bias[col];
          if (MODE == 1) v = 0.5f * v * (1.f + erff(v * 0.70710678118f));
          ((bf16_t*)outp)[(size_t)row * N + col] = (bf16_t)v;
        }
      }
    }
  }
}

// ---------------------------------------------------------------------------
// V transpose: qkv[b, s, 2048 + h*64 + d] -> vt[(b*16+h)*64 + d, s] — unchanged
// ---------------------------------------------------------------------------
__global__ __launch_bounds__(256)
void transpose_v(const bf16_t* __restrict__ qkv, bf16_t* __restrict__ vt) {
  __shared__ bf16_t tile[64][65];
  const int bid = blockIdx.x;
  const int st = bid & 31, h = (bid >> 5) & 15, b = bid >> 9;
  const int tid = threadIdx.x;
  const int r = tid >> 3, c0 = (tid & 7) * 8;
#pragma unroll
  for (int p = 0; p < 2; ++p) {
    int rr = p * 32 + r;
    const bf16_t* g = qkv + (size_t)(b * 2048 + st * 64 + rr) * 3072 + 2048 + h * 64 + c0;
    bf16x8 v = *(const bf16x8*)g;
#pragma unroll
    for (int i = 0; i < 8; ++i) tile[rr][c0 + i] = v[i];
  }
  __syncthreads();
#pragma unroll
  for (int p = 0; p < 2; ++p) {
    int d = p * 32 + r;
    bf16x8 o;
#pragma unroll
    for (int i = 0; i < 8; ++i) o[i] = tile[c0 + i][d];
    *(bf16x8*)(vt + ((size_t)(b * 16 + h) * 64 + d) * 2048 + st * 64 + c0) = o;
  }
}

// ---------------------------------------------------------------------------
// Flash attention with additive relative bias — counted-vmcnt pipeline v3.
// Grid 512, 8 waves. XCD x = bid&7 owns heads {2x,2x+1} (K/V L2-resident).
// Bias held in registers (bbA/bbB, constant-indexed via macro body — never
// address-taken, so asm "memory" clobbers cannot spill them). 16 bias dword
// loads/iter stay in flight across the barrier via s_waitcnt vmcnt(16).
// ---------------------------------------------------------------------------
#define ATTN_BODY(KT, BC, BN)                                                  \
  {                                                                            \
    const int cur_ = (KT) & 1;                                                 \
    const int ktn_ = ((KT) + 1 < 32) ? (KT) + 1 : 31;                          \
    stageKV(ktn_, cur_ ^ 1);                                                   \
    __builtin_amdgcn_sched_barrier(0);                                         \
    {                                                                          \
      const float* bp_ = bias0 + (size_t)ktn_ * 64;                            \
      _Pragma("unroll")                                                        \
      for (int ni = 0; ni < 4; ++ni) {                                         \
        _Pragma("unroll")                                                      \
        for (int j = 0; j < 4; ++j)                                            \
          BN[ni][j] = bp_[(size_t)j * 2048 + ni * 16];                         \
      }                                                                        \
    }                                                                          \
    __builtin_amdgcn_sched_barrier(0);                                         \
    const bf16_t* Kcur_ = (const bf16_t*)((const char*)Ks + cur_ * 8192);      \
    const bf16_t* Vcur_ = (const bf16_t*)((const char*)Vs + cur_ * 8192);      \
    f32x4 sc_v[4];                                                             \
    _Pragma("unroll")                                                          \
    for (int ni = 0; ni < 4; ++ni) sc_v[ni] = zero;                            \
    __builtin_amdgcn_s_setprio(1);                                             \
    _Pragma("unroll")                                                          \
    for (int ks = 0; ks < 2; ++ks) {                                           \
      _Pragma("unroll")                                                        \
      for (int ni = 0; ni < 4; ++ni) {                                         \
        bf16x8 kb_ = lds_read8_sw(Kcur_, ni * 16 + lm, ks * 4 + lk);           \
        sc_v[ni] = __builtin_amdgcn_mfma_f32_16x16x32_bf16(qa[ks], kb_, sc_v[ni], 0, 0, 0); \
      }                                                                        \
    }                                                                          \
    __builtin_amdgcn_s_setprio(0);                                             \
    _Pragma("unroll")                                                          \
    for (int ni = 0; ni < 4; ++ni) {                                           \
      _Pragma("unroll")                                                        \
      for (int j = 0; j < 4; ++j)                                              \
        sc_v[ni][j] = sc_v[ni][j] * 0.125f + BC[ni][j];                        \
    }                                                                          \
    float mloc_[4], rs_[4], scl_[4];                                           \
    _Pragma("unroll")                                                          \
    for (int j = 0; j < 4; ++j)                                                \
      mloc_[j] = fmaxf(fmaxf(sc_v[0][j], sc_v[1][j]), fmaxf(sc_v[2][j], sc_v[3][j])); \
    _Pragma("unroll")                                                          \
    for (int off = 1; off < 16; off <<= 1) {                                   \
      _Pragma("unroll")                                                        \
      for (int j = 0; j < 4; ++j)                                              \
        mloc_[j] = fmaxf(mloc_[j], __shfl_xor(mloc_[j], off, 64));             \
    }                                                                          \
    _Pragma("unroll")                                                          \
    for (int j = 0; j < 4; ++j) {                                              \
      float mnew_ = fmaxf(m_run[j], mloc_[j]);                                 \
      scl_[j] = __expf(m_run[j] - mnew_);                                      \
      m_run[j] = mnew_;                                                        \
      rs_[j] = 0.f;                                                            \
      _Pragma("unroll")                                                        \
      for (int ni = 0; ni < 4; ++ni) {                                         \
        sc_v[ni][j] = __expf(sc_v[ni][j] - mnew_);                             \
        rs_[j] += sc_v[ni][j];                                                 \
      }                                                                        \
    }                                                                          \
    _Pragma("unroll")                                                          \
    for (int off = 1; off < 16; off <<= 1) {                                   \
      _Pragma("unroll")                                                        \
      for (int j = 0; j < 4; ++j)                                              \
        rs_[j] += __shfl_xor(rs_[j], off, 64);                                 \
    }                                                                          \
    _Pragma("unroll")                                                          \
    for (int j = 0; j < 4; ++j) l_run[j] = l_run[j] * scl_[j] + rs_[j];        \
    _Pragma("unroll")                                                          \
    for (int nf = 0; nf < 4; ++nf) {                                           \
      _Pragma("unroll")                                                        \
      for (int j = 0; j < 4; ++j) acc_o[nf][j] *= scl_[j];                     \
    }                                                                          \
    _Pragma("unroll")                                                          \
    for (int ni = 0; ni < 4; ++ni) {                                           \
      _Pragma("unroll")                                                        \
      for (int j = 0; j < 4; ++j) {                                            \
        int rr_ = lk * 4 + j;                                                  \
        *(bf16_t*)((char*)PsW + rr_ * 128 +                                    \
                   (((ni * 2 + (lm >> 3)) ^ (rr_ & 7)) << 4) + (lm & 7) * 2)   \
            = (bf16_t)sc_v[ni][j];                                             \
      }                                                                        \
    }                                                                          \
    _Pragma("unroll")                                                          \
    for (int ks = 0; ks < 2; ++ks) {                                           \
      bf16x8 pa_ = lds_read8_sw(PsW, lm, ks * 4 + lk);                         \
      __builtin_amdgcn_s_setprio(1);                                           \
      _Pragma("unroll")                                                        \
      for (int nf = 0; nf < 4; ++nf) {                                         \
        bf16x8 vb_ = lds_read8_sw(Vcur_, nf * 16 + lm, ks * 4 + lk);           \
        acc_o[nf] = __builtin_amdgcn_mfma_f32_16x16x32_bf16(pa_, vb_, acc_o[nf], 0, 0, 0); \
      }                                                                        \
      __builtin_amdgcn_s_setprio(0);                                           \
    }                                                                          \
    asm volatile("s_waitcnt vmcnt(16)" ::: "memory");                          \
    __builtin_amdgcn_s_barrier();                                              \
    asm volatile("" ::: "memory");                                             \
  }

__global__ __launch_bounds__(512, 4)
void attn_k(const bf16_t* __restrict__ qkv, const bf16_t* __restrict__ vt,
            const float* __restrict__ bias, bf16_t* __restrict__ outp) {
  __shared__ bf16_t Ks[2][64 * 64];          // 16 KB
  __shared__ bf16_t Vs[2][64 * 64];          // 16 KB
  __shared__ bf16_t Ps[8][16 * 64];          // 16 KB

  const int bid = blockIdx.x;                // XCD-grouped decode
  const int x  = bid & 7;                    // XCD (round-robin dispatch)
  const int r_ = bid >> 3;                   // 0..63
  const int h  = x * 2 + (r_ & 1);
  const int b  = (r_ >> 1) & 1;
  const int qt = r_ >> 2;                    // 0..15

  const int tid = threadIdx.x;               // 0..511
  const int lane = tid & 63, wid = tid >> 6;
  const int lm = lane & 15, lk = lane >> 4;

  // K/V staging (inverse-swizzled global source, linear LDS dest)
  const int sr  = tid >> 3;                       // 0..63
  const int sc_ = (((tid & 7) ^ (sr & 7)) * 8);
  const bf16_t* kgb = qkv + 1024 + (size_t)(b * 2048 + sr) * 3072 + h * 64 + sc_;
  const bf16_t* vgb = vt + ((size_t)((b * 16 + h) * 64) + sr) * 2048 + sc_;

  auto stageKV = [&](int kt, int buf) {
    lds_load16(kgb + (size_t)(kt * 64) * 3072, (char*)Ks + buf * 8192 + wid * 1024);
    lds_load16(vgb + kt * 64,                  (char*)Vs + buf * 8192 + wid * 1024);
  };

  // Q fragments direct from global (one-time)
  bf16x8 qa[2];
#pragma unroll
  for (int ks = 0; ks < 2; ++ks)
    qa[ks] = *(const bf16x8*)(qkv +
        (size_t)(b * 2048 + qt * 128 + wid * 16 + lm) * 3072 + h * 64 + ks * 32 + lk * 8);

  f32x4 zero = {0.f, 0.f, 0.f, 0.f};
  f32x4 acc_o[4];
  float m_run[4], l_run[4];
#pragma unroll
  for (int j = 0; j < 4; ++j) { acc_o[j] = zero; m_run[j] = -1e30f; l_run[j] = 0.f; }

  bf16_t* PsW = &Ps[wid][0];
  const float* bias0 = bias + (size_t)h * 2048 * 2048 +
                       (size_t)(qt * 128 + wid * 16 + lk * 4) * 2048 + lm;

  float bbA[4][4], bbB[4][4];

  // ---- prologue: stage tile 0, bias tile 0 -> bbA ----
  stageKV(0, 0);
  __builtin_amdgcn_sched_barrier(0);
#pragma unroll
  for (int ni = 0; ni < 4; ++ni)
#pragma unroll
    for (int j = 0; j < 4; ++j)
      bbA[ni][j] = bias0[(size_t)j * 2048 + ni * 16];
  __builtin_amdgcn_sched_barrier(0);
  asm volatile("s_waitcnt vmcnt(16)" ::: "memory");  // stage(0) done; bias in flight
  __builtin_amdgcn_s_barrier();
  asm volatile("" ::: "memory");

  for (int kt2 = 0; kt2 < 32; kt2 += 2) {
    ATTN_BODY(kt2,     bbA, bbB)
    ATTN_BODY(kt2 + 1, bbB, bbA)
  }

#pragma unroll
  for (int nf = 0; nf < 4; ++nf) {
#pragma unroll
    for (int j = 0; j < 4; ++j) {
      float o = acc_o[nf][j] / l_run[j];
      outp[(size_t)(b * 2048 + qt * 128 + wid * 16 + lk * 4 + j) * 1024 + h * 64 + nf * 16 + lm] = (bf16_t)o;
    }
  }
}
#undef ATTN_BODY

// ---------------------------------------------------------------------------
// Fused LayerNorm over last dim (1024):  in = pa + pb + bias + resid — unchanged
// ---------------------------------------------------------------------------
__global__ __launch_bounds__(256)
void layernorm2_k(const float* __restrict__ pa, const float* __restrict__ pb,
                  const float* __restrict__ bias, const float* __restrict__ resid,
                  const float* __restrict__ gamma, const float* __restrict__ beta,
                  float* __restrict__ out32, bf16_t* __restrict__ out16) {
  const int row = blockIdx.x, tid = threadIdx.x;
  const int lane = tid & 63, wid = tid >> 6;
  const size_t base = (size_t)row * 1024;
  float4 v  = ((const float4*)(pa + base))[tid];
  float4 v2 = ((const float4*)(pb + base))[tid];
  float4 bb = ((const float4*)bias)[tid];
  float4 rr = ((const float4*)(resid + base))[tid];
  v.x += v2.x + bb.x + rr.x;
  v.y += v2.y + bb.y + rr.y;
  v.z += v2.z + bb.z + rr.z;
  v.w += v2.w + bb.w + rr.w;
  float s  = v.x + v.y + v.z + v.w;
  float s2 = v.x * v.x + v.y * v.y + v.z * v.z + v.w * v.w;
#pragma unroll
  for (int off = 32; off; off >>= 1) {
    s  += __shfl_xor(s, off, 64);
    s2 += __shfl_xor(s2, off, 64);
  }
  __shared__ float red[8];
  if (lane == 0) { red[wid] = s; red[wid + 4] = s2; }
  __syncthreads();
  s  = red[0] + red[1] + red[2] + red[3];
  s2 = red[4] + red[5] + red[6] + red[7];
  const float mu  = s * (1.f / 1024.f);
  const float inv = rsqrtf(s2 * (1.f / 1024.f) - mu * mu + 1e-5f);
  const float4 g4 = ((const float4*)gamma)[tid];
  const float4 b4 = ((const float4*)beta)[tid];
  float4 o;
  o.x = (v.x - mu) * inv * g4.x + b4.x;
  o.y = (v.y - mu) * inv * g4.y + b4.y;
  o.z = (v.z - mu) * inv * g4.z + b4.z;
  o.w = (v.w - mu) * inv * g4.w + b4.w;
  ((float4*)(out32 + base))[tid] = o;
  if (out16) {
    bf16x4 ob = {(bf16_t)o.x, (bf16_t)o.y, (bf16_t)o.z, (bf16_t)o.w};
    *(bf16x4*)(out16 + base + tid * 4) = ob;
  }
}

// ---------------------------------------------------------------------------
extern "C" void kernel_launch(void* const* d_in, const int* in_sizes, int n_in,
                              void* d_out, int out_size, void* d_ws, size_t ws_size,
                              hipStream_t stream) {
  const float* src  = (const float*)d_in[0];
  const float* rbias= (const float*)d_in[1];
  const float* Wq   = (const float*)d_in[2];
  const float* bq   = (const float*)d_in[3];
  const float* Wk   = (const float*)d_in[4];
  const float* bk   = (const float*)d_in[5];
  const float* Wv   = (const float*)d_in[6];
  const float* bv   = (const float*)d_in[7];
  const float* Wo   = (const float*)d_in[8];
  const float* bo   = (const float*)d_in[9];
  const float* W1   = (const float*)d_in[10];
  const float* b1   = (const float*)d_in[11];
  const float* W2   = (const float*)d_in[12];
  const float* b2   = (const float*)d_in[13];
  const float* g1   = (const float*)d_in[14];
  const float* be1  = (const float*)d_in[15];
  const float* g2   = (const float*)d_in[16];
  const float* be2  = (const float*)d_in[17];

  char* ws = (char*)d_ws;
  const size_t MB = 1u << 20;
  bf16_t* src_bf  = (bf16_t*)(ws + 0);        //  8 MB [4096,1024]
  bf16_t* wqkv_bf = (bf16_t*)(ws + 8 * MB);   //  6 MB [3072,1024]
  bf16_t* wo_bf   = (bf16_t*)(ws + 14 * MB);  //  2 MB
  bf16_t* w1_bf   = (bf16_t*)(ws + 16 * MB);  //  8 MB [4096,1024]
  bf16_t* w2_bf   = (bf16_t*)(ws + 24 * MB);  //  8 MB [1024,4096]
  float*  bqkv    = (float*)(ws + 32 * MB);   // 12 KB
  bf16_t* qkv_bf  = (bf16_t*)(ws + 33 * MB);  // 24 MB [4096,3072]
  bf16_t* vt      = (bf16_t*)(ws + 57 * MB);  //  8 MB [32*64,2048]
  bf16_t* attn_bf = (bf16_t*)(ws + 65 * MB);  //  8 MB [4096,1024]
  float*  pA      = (float*)(ws + 73 * MB);   // 16 MB split-K partial 0
  float*  pB      = (float*)(ws + 89 * MB);   // 16 MB split-K partial 1
  float*  xf      = (float*)(ws + 105 * MB);  // 16 MB
  bf16_t* x_bf    = (bf16_t*)(ws + 121 * MB); //  8 MB
  bf16_t* h_bf    = (bf16_t*)(ws + 129 * MB); // 32 MB [4096,4096]  (total 161)

  auto cvt = [&](const float* s, bf16_t* d, int n) {
    f32_to_bf16_k<<<n / 1024, 256, 0, stream>>>(s, d, n);
  };
  cvt(src, src_bf, 4096 * 1024);
  cvt(Wq, wqkv_bf,                   1024 * 1024);
  cvt(Wk, wqkv_bf + 1024 * 1024,     1024 * 1024);
  cvt(Wv, wqkv_bf + 2 * 1024 * 1024, 1024 * 1024);
  cvt(Wo, wo_bf, 1024 * 1024);
  cvt(W1, w1_bf, 4096 * 1024);
  cvt(W2, w2_bf, 4096 * 1024);
  copy_f32_k<<<4, 256, 0, stream>>>(bq, bqkv, 1024);
  copy_f32_k<<<4, 256, 0, stream>>>(bk, bqkv + 1024, 1024);
  copy_f32_k<<<4, 256, 0, stream>>>(bv, bqkv + 2048, 1024);

  // fused QKV projection: [4096,3072]
  gemm_bt<0><<<dim3(24, 32), 256, 0, stream>>>(
      src_bf, 1024, wqkv_bf, 1024, bqkv, qkv_bf, 4096, 3072, 1024);
  transpose_v<<<1024, 256, 0, stream>>>(qkv_bf, vt);
  attn_k<<<512, 512, 0, stream>>>(qkv_bf, vt, rbias, attn_bf);

  // output projection, split-K=2 -> partials; LN1 fuses +bo+src
  gemm_bt<3><<<dim3(8, 32, 2), 256, 0, stream>>>(
      attn_bf, 1024, wo_bf, 1024, nullptr, pA, 4096, 1024, 512);
  layernorm2_k<<<4096, 256, 0, stream>>>(pA, pB, bo, src, g1, be1, xf, x_bf);

  // FFN1 + exact GELU
  gemm_bt<1><<<dim3(32, 32), 256, 0, stream>>>(
      x_bf, 1024, w1_bf, 1024, b1, h_bf, 4096, 4096, 1024);

  // FFN2, split-K=2 -> partials; LN2 fuses +b2+xf
  gemm_bt<3><<<dim3(8, 32, 2), 256, 0, stream>>>(
      h_bf, 4096, w2_bf, 4096, nullptr, pA, 4096, 1024, 2048);
  layernorm2_k<<<4096, 256, 0, stream>>>(pA, pB, b2, xf, g2, be2, (float*)d_out, nullptr);
}